// Round 4
// baseline (200.637 us; speedup 1.0000x reference)
//
#include <hip/hip_runtime.h>
#include <hip/hip_bf16.h>
#include <math.h>

// ---------------------------------------------------------------------------
// Round 11: back to r8 (best measured: 116us, MfmaUtil 18.7, 2 waves/SIMD,
// no spill) -- the 4-wave half-weight experiments (r9/r10) are dead: at
// launch_bounds(256,3) the allocator splits 170 regs into ~84 arch + ~84
// accum and spills the loop (WRITE_SIZE 46-52 MB, VGPR_Count=84, occupancy
// never reached 3 waves/SIMD). Occupancy is register-walled at 2/SIMD.
// This round attacks r8's stall at fixed occupancy: TILE PAIRS per barrier.
//   - 27 barriers instead of 52 (halved rendezvous overhead)
//   - producer: build Y1(t1) BETWEEN mfma(t0) and pack(t0): independent
//     VALU fills the MFMA shadow (in-order issue has work to issue)
//   - consumer: both tiles' ds_read_b128 issued up front: 2nd read's
//     ~120cyc latency hides under 1st tile's MFMA
//   - s_setprio(1) around MFMA clusters (T5: P/C roles are diverse)
// Y2: 2 parities x 2 slots (16 KB). Producer writes parity j&1 in window j;
// consumer reads parity (j-1)&1 -- disjoint, rewrite 2 barriers after last
// read. 51 = 25 pairs + 1 single tail (j=25).
// Numerics: identical chain to r8 (absmax 0.125 vs thr 0.4725).
// ---------------------------------------------------------------------------

#define B_N    16384
#define KQ     51
#define HD     128
#define IND    64
#define BLK    128               // 2 waves: producer + consumer
#define RPB    16                // b-rows per block
#define GRID   (B_N / RPB)       // 1024
#define TPB    ((RPB * KQ) / 16) // 51 tiles per block (exact)
#define NPAIR  26                // ceil(51/2): pair j covers tiles 2j,2j+1

typedef __attribute__((ext_vector_type(8))) short short8;
typedef __attribute__((ext_vector_type(4))) float f32x4;

union S8U { short8 s8; unsigned u[4]; };

__device__ __forceinline__ unsigned short f2bf(float f) {
    __hip_bfloat16 t = __float2bfloat16(f);
    return *reinterpret_cast<unsigned short*>(&t);
}

#if defined(__gfx950__) && defined(__has_builtin)
#if __has_builtin(__builtin_amdgcn_cvt_pk_bf16_f32)
#define HAVE_PK_BF16 1
#endif
#endif

__device__ __forceinline__ unsigned pk_bf16(float lo, float hi) {
#ifdef HAVE_PK_BF16
    typedef __attribute__((ext_vector_type(2))) __bf16 bfv2;
    bfv2 r = __builtin_amdgcn_cvt_pk_bf16_f32(lo, hi);
    return *reinterpret_cast<unsigned*>(&r);
#else
    return (unsigned)f2bf(lo) | ((unsigned)f2bf(hi) << 16);
#endif
}

__device__ __forceinline__ float bf_lo(unsigned u) {
    return __uint_as_float(u << 16);
}
__device__ __forceinline__ float bf_hi(unsigned u) {
    return __uint_as_float(u & 0xffff0000u);
}

__launch_bounds__(BLK, 2)
__global__ void umnn_fused(const float* __restrict__ x,  const float* __restrict__ h,
                           const float* __restrict__ W1, const float* __restrict__ b1,
                           const float* __restrict__ W2, const float* __restrict__ b2,
                           const float* __restrict__ W3, const float* __restrict__ b3,
                           const float* __restrict__ W4, const float* __restrict__ b4,
                           float* __restrict__ out)
{
    __shared__ __align__(16) float hpL[RPB * HD];      // 8 KB block hpart
    __shared__ __align__(16) char  y2x[2][8192];       // 16 KB: 2 parities x 2 slots
    __shared__ __align__(16) float hshT[63 * 20];      // 5 KB h^T staging
    __shared__ float vs[RPB * KQ + 16];                // y4 partials (consumer)
    __shared__ float xL[RPB];
    __shared__ float sSteps[KQ], sCcw[KQ];
    __shared__ float red2[2];

    const int tid  = threadIdx.x;
    const int w    = tid >> 6;
    const int lane = tid & 63;
    const int q    = lane >> 4;
    const int lm   = lane & 15;
    const int swz  = lm & 7;
    const int rowBase = blockIdx.x * RPB;

    // ---- CC tables (validated r4 formula) ----
    if (tid < KQ) {
        const int j = tid;
        const float pi50 = 0.06283185307179586f;
        sSteps[j] = __cosf((float)j * pi50);
        float s = 0.0f;
        for (int i = 0; i <= 50; i += 2) {
            float Wi = (i == 0) ? 1.0f : 2.0f / (1.0f - (float)(i * i));
            float lam;
            if (j == 0) lam = 0.5f;
            else {
                int mp = (i * j) % 100;
                lam = __cosf((float)mp * pi50);
                if (j == 50) lam *= 0.5f;
            }
            s += (lam * 0.04f) * Wi;
        }
        sCcw[j] = s;
    }
    // ---- xmax scan (x: 64 KB, cache-resident) ----
    {
        const f32x4* x4 = (const f32x4*)x;
        float mx = -1e30f;
        for (int i = tid; i < B_N / 4; i += BLK) {
            f32x4 v = x4[i];
            mx = fmaxf(fmaxf(mx, fmaxf(v[0], v[1])), fmaxf(v[2], v[3]));
        }
        #pragma unroll
        for (int d = 32; d > 0; d >>= 1) mx = fmaxf(mx, __shfl_xor(mx, d));
        if (lane == 0) red2[w] = mx;
    }
    // ---- stage h^T for this block's 16 rows; init xL ----
    for (int i = tid; i < RPB * 63; i += BLK) {
        int r = i / 63, d = i - r * 63;
        hshT[d * 20 + r] = h[rowBase * 63 + i];
    }
    if (tid < RPB) xL[tid] = x[rowBase + tid];
    __syncthreads();                                   // B1

    const float xmax = fmaxf(red2[0], red2[1]) + 10.0f;

    // ---- block hpart: thread tid = feature n, 16 row-accumulators ----
    {
        const int n = tid;
        float acc[RPB];
        const float b1v = b1[n];
        #pragma unroll
        for (int r = 0; r < RPB; ++r) acc[r] = b1v;
        const float* wr = W1 + n * IND + 1;
        #pragma unroll 1
        for (int d = 0; d < IND - 1; ++d) {
            float wv = wr[d];
            const float* ht = hshT + d * 20;
            #pragma unroll
            for (int rc = 0; rc < RPB / 4; ++rc) {
                f32x4 hv = *(const f32x4*)(ht + rc * 4);
                acc[rc * 4 + 0] = fmaf(wv, hv[0], acc[rc * 4 + 0]);
                acc[rc * 4 + 1] = fmaf(wv, hv[1], acc[rc * 4 + 1]);
                acc[rc * 4 + 2] = fmaf(wv, hv[2], acc[rc * 4 + 2]);
                acc[rc * 4 + 3] = fmaf(wv, hv[3], acc[rc * 4 + 3]);
            }
        }
        #pragma unroll
        for (int r = 0; r < RPB; ++r) hpL[r * HD + n] = acc[r];
    }
    __syncthreads();                                   // B2 (hpL ready)

    if (w == 0) {
        // ================= PRODUCER: layer 1 + layer 2 =================
        float w1x[32];
        #pragma unroll
        for (int kk = 0; kk < 4; ++kk)
            #pragma unroll
            for (int j = 0; j < 8; ++j)
                w1x[kk * 8 + j] = W1[(kk * 32 + q * 8 + j) * IND];

        short8  W2A[8][4];
        unsigned b2p[16];
        #pragma unroll
        for (int nt = 0; nt < 8; ++nt) {
            #pragma unroll
            for (int kk = 0; kk < 4; ++kk) {
                const float* p2 = W2 + (nt * 16 + lm) * HD + kk * 32 + q * 8;
                S8U a2;
                #pragma unroll
                for (int j = 0; j < 4; ++j)
                    a2.u[j] = pk_bf16(p2[2 * j], p2[2 * j + 1]);
                W2A[nt][kk] = a2.s8;
            }
            b2p[2 * nt + 0] = pk_bf16(b2[nt * 16 + q * 4 + 0], b2[nt * 16 + q * 4 + 1]);
            b2p[2 * nt + 1] = pk_bf16(b2[nt * 16 + q * 4 + 2], b2[nt * 16 + q * 4 + 3]);
        }
        int wrOff[8];
        #pragma unroll
        for (int nt = 0; nt < 8; ++nt)
            wrOff[nt] = lm * 256 + (((2 * nt + (q >> 1)) ^ swz) << 4) + ((q & 1) << 3);

        auto buildY1 = [&](int t, short8* Y) {
            const int s   = t * 16 + lm;               // <= 50*16+15 = 815
            const unsigned row = (unsigned)s / KQ;     // 0..15
            const int k   = s - (int)row * KQ;
            const float x0 = xL[row];
            const float X  = fmaf((xmax - x0) * 0.5f, sSteps[k] + 1.0f, x0);
            #pragma unroll
            for (int kk = 0; kk < 4; ++kk) {
                const float* hp = hpL + row * HD + kk * 32 + q * 8;
                f32x4 ha = *(const f32x4*)hp;
                f32x4 hb = *(const f32x4*)(hp + 4);
                S8U u;
                u.u[0] = pk_bf16(fmaxf(fmaf(X, w1x[kk*8+0], ha[0]), 0.f),
                                 fmaxf(fmaf(X, w1x[kk*8+1], ha[1]), 0.f));
                u.u[1] = pk_bf16(fmaxf(fmaf(X, w1x[kk*8+2], ha[2]), 0.f),
                                 fmaxf(fmaf(X, w1x[kk*8+3], ha[3]), 0.f));
                u.u[2] = pk_bf16(fmaxf(fmaf(X, w1x[kk*8+4], hb[0]), 0.f),
                                 fmaxf(fmaf(X, w1x[kk*8+5], hb[1]), 0.f));
                u.u[3] = pk_bf16(fmaxf(fmaf(X, w1x[kk*8+6], hb[2]), 0.f),
                                 fmaxf(fmaf(X, w1x[kk*8+7], hb[3]), 0.f));
                Y[kk] = u.s8;
            }
        };

        #pragma unroll 1
        for (int j = 0; j <= NPAIR; ++j) {             // 27 iterations
            if (j < NPAIR) {
                const int t0 = 2 * j;
                const bool two = (t0 + 1 < TPB);
                char* d2 = y2x[j & 1];

                short8 Y1a[4];
                buildY1(t0, Y1a);

                f32x4 C[8];
                #pragma unroll
                for (int nt = 0; nt < 8; ++nt) {
                    unsigned u0 = b2p[2 * nt], u1 = b2p[2 * nt + 1];
                    C[nt][0] = bf_lo(u0); C[nt][1] = bf_hi(u0);
                    C[nt][2] = bf_lo(u1); C[nt][3] = bf_hi(u1);
                }
                __builtin_amdgcn_s_setprio(1);
                #pragma unroll
                for (int kk = 0; kk < 4; ++kk)
                    #pragma unroll
                    for (int nt = 0; nt < 8; ++nt)
                        C[nt] = __builtin_amdgcn_mfma_f32_16x16x32_bf16(W2A[nt][kk], Y1a[kk], C[nt], 0, 0, 0);
                __builtin_amdgcn_s_setprio(0);

                // independent VALU for the MFMA shadow: next tile's Y1
                short8 Y1b[4];
                if (two) buildY1(t0 + 1, Y1b);

                #pragma unroll
                for (int nt = 0; nt < 8; ++nt) {
                    unsigned lo = pk_bf16(fmaxf(C[nt][0], 0.f), fmaxf(C[nt][1], 0.f));
                    unsigned hi = pk_bf16(fmaxf(C[nt][2], 0.f), fmaxf(C[nt][3], 0.f));
                    *(int2*)(d2 + wrOff[nt]) = make_int2((int)lo, (int)hi);
                }

                if (two) {
                    #pragma unroll
                    for (int nt = 0; nt < 8; ++nt) {
                        unsigned u0 = b2p[2 * nt], u1 = b2p[2 * nt + 1];
                        C[nt][0] = bf_lo(u0); C[nt][1] = bf_hi(u0);
                        C[nt][2] = bf_lo(u1); C[nt][3] = bf_hi(u1);
                    }
                    __builtin_amdgcn_s_setprio(1);
                    #pragma unroll
                    for (int kk = 0; kk < 4; ++kk)
                        #pragma unroll
                        for (int nt = 0; nt < 8; ++nt)
                            C[nt] = __builtin_amdgcn_mfma_f32_16x16x32_bf16(W2A[nt][kk], Y1b[kk], C[nt], 0, 0, 0);
                    __builtin_amdgcn_s_setprio(0);
                    #pragma unroll
                    for (int nt = 0; nt < 8; ++nt) {
                        unsigned lo = pk_bf16(fmaxf(C[nt][0], 0.f), fmaxf(C[nt][1], 0.f));
                        unsigned hi = pk_bf16(fmaxf(C[nt][2], 0.f), fmaxf(C[nt][3], 0.f));
                        *(int2*)(d2 + 4096 + wrOff[nt]) = make_int2((int)lo, (int)hi);
                    }
                }
            }
            __syncthreads();                           // phase barrier
        }
    } else {
        // ================= CONSUMER: layer 3 + layer 4 =================
        short8  W3A[8][4];
        unsigned b3p[16];
        f32x4   W4c[8];
        #pragma unroll
        for (int nt = 0; nt < 8; ++nt) {
            #pragma unroll
            for (int kk = 0; kk < 4; ++kk) {
                const float* p3 = W3 + (nt * 16 + lm) * HD + kk * 32 + q * 8;
                S8U a3;
                #pragma unroll
                for (int j = 0; j < 4; ++j)
                    a3.u[j] = pk_bf16(p3[2 * j], p3[2 * j + 1]);
                W3A[nt][kk] = a3.s8;
            }
            b3p[2 * nt + 0] = pk_bf16(b3[nt * 16 + q * 4 + 0], b3[nt * 16 + q * 4 + 1]);
            b3p[2 * nt + 1] = pk_bf16(b3[nt * 16 + q * 4 + 2], b3[nt * 16 + q * 4 + 3]);
            W4c[nt] = *(const f32x4*)(W4 + nt * 16 + q * 4);
        }
        const float b4v = b4[0];
        int rdOff[4];
        #pragma unroll
        for (int kk = 0; kk < 4; ++kk)
            rdOff[kk] = lm * 256 + (((kk * 4 + q) ^ swz) << 4);

        #pragma unroll 1
        for (int j = 0; j <= NPAIR; ++j) {             // 27 iterations
            if (j >= 1) {
                const int pr = j - 1;
                const int t0 = 2 * pr;
                const bool two = (t0 + 1 < TPB);
                const char* s2 = y2x[pr & 1];

                // issue both tiles' reads up front: 2nd latency hides
                short8 Ya[4], Yb[4];
                #pragma unroll
                for (int kk = 0; kk < 4; ++kk)
                    Ya[kk] = *(const short8*)(s2 + rdOff[kk]);
                if (two) {
                    #pragma unroll
                    for (int kk = 0; kk < 4; ++kk)
                        Yb[kk] = *(const short8*)(s2 + 4096 + rdOff[kk]);
                }

                f32x4 C[8];
                #pragma unroll
                for (int nt = 0; nt < 8; ++nt) {
                    unsigned u0 = b3p[2 * nt], u1 = b3p[2 * nt + 1];
                    C[nt][0] = bf_lo(u0); C[nt][1] = bf_hi(u0);
                    C[nt][2] = bf_lo(u1); C[nt][3] = bf_hi(u1);
                }
                __builtin_amdgcn_s_setprio(1);
                #pragma unroll
                for (int kk = 0; kk < 4; ++kk)
                    #pragma unroll
                    for (int nt = 0; nt < 8; ++nt)
                        C[nt] = __builtin_amdgcn_mfma_f32_16x16x32_bf16(W3A[nt][kk], Ya[kk], C[nt], 0, 0, 0);
                __builtin_amdgcn_s_setprio(0);

                float pa = 0.f;
                #pragma unroll
                for (int nt = 0; nt < 8; ++nt) {
                    pa = fmaf(fmaxf(C[nt][0], 0.f), W4c[nt][0], pa);
                    pa = fmaf(fmaxf(C[nt][1], 0.f), W4c[nt][1], pa);
                    pa = fmaf(fmaxf(C[nt][2], 0.f), W4c[nt][2], pa);
                    pa = fmaf(fmaxf(C[nt][3], 0.f), W4c[nt][3], pa);
                }
                pa += __shfl_xor(pa, 16);
                pa += __shfl_xor(pa, 32);
                if (lane < 16) vs[t0 * 16 + lm] = pa;

                if (two) {
                    #pragma unroll
                    for (int nt = 0; nt < 8; ++nt) {
                        unsigned u0 = b3p[2 * nt], u1 = b3p[2 * nt + 1];
                        C[nt][0] = bf_lo(u0); C[nt][1] = bf_hi(u0);
                        C[nt][2] = bf_lo(u1); C[nt][3] = bf_hi(u1);
                    }
                    __builtin_amdgcn_s_setprio(1);
                    #pragma unroll
                    for (int kk = 0; kk < 4; ++kk)
                        #pragma unroll
                        for (int nt = 0; nt < 8; ++nt)
                            C[nt] = __builtin_amdgcn_mfma_f32_16x16x32_bf16(W3A[nt][kk], Yb[kk], C[nt], 0, 0, 0);
                    __builtin_amdgcn_s_setprio(0);

                    float pb = 0.f;
                    #pragma unroll
                    for (int nt = 0; nt < 8; ++nt) {
                        pb = fmaf(fmaxf(C[nt][0], 0.f), W4c[nt][0], pb);
                        pb = fmaf(fmaxf(C[nt][1], 0.f), W4c[nt][1], pb);
                        pb = fmaf(fmaxf(C[nt][2], 0.f), W4c[nt][2], pb);
                        pb = fmaf(fmaxf(C[nt][3], 0.f), W4c[nt][3], pb);
                    }
                    pb += __shfl_xor(pb, 16);
                    pb += __shfl_xor(pb, 32);
                    if (lane < 16) vs[(t0 + 1) * 16 + lm] = pb;
                }
            }
            __syncthreads();                           // phase barrier
        }

        // ---- deferred epilogue (consumer wave): elu + ccw + row-reduce ----
        {
            const int r   = lane >> 2;                 // row 0..15
            const int sub = lane & 3;
            float a = 0.f;
            #pragma unroll 1
            for (int j = 0; j < 13; ++j) {
                int k = sub + 4 * j;
                if (k < KQ) {
                    float y4 = vs[r * KQ + k] + b4v;
                    float f  = (y4 > 0.f) ? (y4 + 1.f) : __expf(y4);
                    a = fmaf(f, sCcw[k], a);
                }
            }
            a += __shfl_xor(a, 1);
            a += __shfl_xor(a, 2);
            if (sub == 0)
                out[rowBase + r] = a * (xmax - xL[r]) * 0.5f;
        }
    }
}

// ---------------------------------------------------------------------------
extern "C" void kernel_launch(void* const* d_in, const int* in_sizes, int n_in,
                              void* d_out, int out_size, void* d_ws, size_t ws_size,
                              hipStream_t stream)
{
    const float* x  = (const float*)d_in[0];
    const float* h  = (const float*)d_in[1];
    const float* W1 = (const float*)d_in[2];
    const float* b1 = (const float*)d_in[3];
    const float* W2 = (const float*)d_in[4];
    const float* b2 = (const float*)d_in[5];
    const float* W3 = (const float*)d_in[6];
    const float* b3 = (const float*)d_in[7];
    const float* W4 = (const float*)d_in[8];
    const float* b4 = (const float*)d_in[9];
    float* out = (float*)d_out;

    umnn_fused<<<GRID, BLK, 0, stream>>>(x, h, W1, b1, W2, b2, W3, b3,
                                         W4, b4, out);
}

// Round 5
// 177.754 us; speedup vs baseline: 1.1287x; 1.1287x over previous
//
#include <hip/hip_runtime.h>
#include <hip/hip_bf16.h>
#include <math.h>

// ---------------------------------------------------------------------------
// Round 12: r8 structure (best measured: 116us rocprof) + WORK REBALANCE.
// r11 post-mortem: pairs+setprio spilled (WRITE 8.8MB) and fought P/C
// overlap; reverted. r8's real imbalance: producer = Y1-build 80 + C-init 32
// + relu+pack 56 = ~168 VALU/tile; consumer = ~70 VALU/tile. Phase clock =
// max(P,C). Fix: hand off layer-2 output RAW FP32 through LDS:
//   producer: build Y1, 32 MFMA, write C[nt] directly (8x ds_write_b128,
//             no relu, no pack)                       -> ~120 VALU/tile
//   consumer: read fp32 tile (8x ds_read_b128), relu+pack into MFMA
//             operands (32 fmax + 16 pk), 32 MFMA, L4 -> ~118 VALU/tile
// Same barrier ladder / parity protocol as r8 (lag-1, double buffer).
// Producer register peak DROPS (pack temps gone) -- no spill expected.
// LDS: c2x = 2 x 8KB fp32 (total ~33KB, still 4 blocks/CU).
// Numerics: bit-identical chain (relu+bf16-round relocated to consumer,
// same values); absmax 0.125 vs thr 0.4725.
// ---------------------------------------------------------------------------

#define B_N    16384
#define KQ     51
#define HD     128
#define IND    64
#define BLK    128               // 2 waves: producer + consumer
#define RPB    16                // b-rows per block
#define GRID   (B_N / RPB)       // 1024
#define TPB    ((RPB * KQ) / 16) // 51 tiles per block (exact)

typedef __attribute__((ext_vector_type(8))) short short8;
typedef __attribute__((ext_vector_type(4))) float f32x4;

union S8U { short8 s8; unsigned u[4]; };

__device__ __forceinline__ unsigned short f2bf(float f) {
    __hip_bfloat16 t = __float2bfloat16(f);
    return *reinterpret_cast<unsigned short*>(&t);
}

#if defined(__gfx950__) && defined(__has_builtin)
#if __has_builtin(__builtin_amdgcn_cvt_pk_bf16_f32)
#define HAVE_PK_BF16 1
#endif
#endif

__device__ __forceinline__ unsigned pk_bf16(float lo, float hi) {
#ifdef HAVE_PK_BF16
    typedef __attribute__((ext_vector_type(2))) __bf16 bfv2;
    bfv2 r = __builtin_amdgcn_cvt_pk_bf16_f32(lo, hi);
    return *reinterpret_cast<unsigned*>(&r);
#else
    return (unsigned)f2bf(lo) | ((unsigned)f2bf(hi) << 16);
#endif
}

__device__ __forceinline__ float bf_lo(unsigned u) {
    return __uint_as_float(u << 16);
}
__device__ __forceinline__ float bf_hi(unsigned u) {
    return __uint_as_float(u & 0xffff0000u);
}

__launch_bounds__(BLK, 2)
__global__ void umnn_fused(const float* __restrict__ x,  const float* __restrict__ h,
                           const float* __restrict__ W1, const float* __restrict__ b1,
                           const float* __restrict__ W2, const float* __restrict__ b2,
                           const float* __restrict__ W3, const float* __restrict__ b3,
                           const float* __restrict__ W4, const float* __restrict__ b4,
                           float* __restrict__ out)
{
    __shared__ __align__(16) float hpL[RPB * HD];      // 8 KB block hpart
    __shared__ __align__(16) char  c2x[2][8192];       // 16 KB fp32 C handoff
    __shared__ __align__(16) float hshT[63 * 20];      // 5 KB h^T staging
    __shared__ float vs[RPB * KQ + 16];                // y4 partials (consumer)
    __shared__ float xL[RPB];
    __shared__ float sSteps[KQ], sCcw[KQ];
    __shared__ float red2[2];

    const int tid  = threadIdx.x;
    const int w    = tid >> 6;
    const int lane = tid & 63;
    const int q    = lane >> 4;
    const int lm   = lane & 15;
    const int swz  = lm & 7;
    const int rowBase = blockIdx.x * RPB;

    // ---- CC tables (validated r4 formula) ----
    if (tid < KQ) {
        const int j = tid;
        const float pi50 = 0.06283185307179586f;
        sSteps[j] = __cosf((float)j * pi50);
        float s = 0.0f;
        for (int i = 0; i <= 50; i += 2) {
            float Wi = (i == 0) ? 1.0f : 2.0f / (1.0f - (float)(i * i));
            float lam;
            if (j == 0) lam = 0.5f;
            else {
                int mp = (i * j) % 100;
                lam = __cosf((float)mp * pi50);
                if (j == 50) lam *= 0.5f;
            }
            s += (lam * 0.04f) * Wi;
        }
        sCcw[j] = s;
    }
    // ---- xmax scan (x: 64 KB, cache-resident) ----
    {
        const f32x4* x4 = (const f32x4*)x;
        float mx = -1e30f;
        for (int i = tid; i < B_N / 4; i += BLK) {
            f32x4 v = x4[i];
            mx = fmaxf(fmaxf(mx, fmaxf(v[0], v[1])), fmaxf(v[2], v[3]));
        }
        #pragma unroll
        for (int d = 32; d > 0; d >>= 1) mx = fmaxf(mx, __shfl_xor(mx, d));
        if (lane == 0) red2[w] = mx;
    }
    // ---- stage h^T for this block's 16 rows; init xL ----
    for (int i = tid; i < RPB * 63; i += BLK) {
        int r = i / 63, d = i - r * 63;
        hshT[d * 20 + r] = h[rowBase * 63 + i];
    }
    if (tid < RPB) xL[tid] = x[rowBase + tid];
    __syncthreads();                                   // B1

    const float xmax = fmaxf(red2[0], red2[1]) + 10.0f;

    // ---- block hpart: thread tid = feature n, 16 row-accumulators ----
    {
        const int n = tid;
        float acc[RPB];
        const float b1v = b1[n];
        #pragma unroll
        for (int r = 0; r < RPB; ++r) acc[r] = b1v;
        const float* wr = W1 + n * IND + 1;
        #pragma unroll 1
        for (int d = 0; d < IND - 1; ++d) {
            float wv = wr[d];
            const float* ht = hshT + d * 20;
            #pragma unroll
            for (int rc = 0; rc < RPB / 4; ++rc) {
                f32x4 hv = *(const f32x4*)(ht + rc * 4);
                acc[rc * 4 + 0] = fmaf(wv, hv[0], acc[rc * 4 + 0]);
                acc[rc * 4 + 1] = fmaf(wv, hv[1], acc[rc * 4 + 1]);
                acc[rc * 4 + 2] = fmaf(wv, hv[2], acc[rc * 4 + 2]);
                acc[rc * 4 + 3] = fmaf(wv, hv[3], acc[rc * 4 + 3]);
            }
        }
        #pragma unroll
        for (int r = 0; r < RPB; ++r) hpL[r * HD + n] = acc[r];
    }
    __syncthreads();                                   // B2 (hpL ready)

    if (w == 0) {
        // ========== PRODUCER: layer 1 + layer 2, raw fp32 handoff ==========
        float w1x[32];
        #pragma unroll
        for (int kk = 0; kk < 4; ++kk)
            #pragma unroll
            for (int j = 0; j < 8; ++j)
                w1x[kk * 8 + j] = W1[(kk * 32 + q * 8 + j) * IND];

        short8  W2A[8][4];
        unsigned b2p[16];
        #pragma unroll
        for (int nt = 0; nt < 8; ++nt) {
            #pragma unroll
            for (int kk = 0; kk < 4; ++kk) {
                const float* p2 = W2 + (nt * 16 + lm) * HD + kk * 32 + q * 8;
                S8U a2;
                #pragma unroll
                for (int j = 0; j < 4; ++j)
                    a2.u[j] = pk_bf16(p2[2 * j], p2[2 * j + 1]);
                W2A[nt][kk] = a2.s8;
            }
            b2p[2 * nt + 0] = pk_bf16(b2[nt * 16 + q * 4 + 0], b2[nt * 16 + q * 4 + 1]);
            b2p[2 * nt + 1] = pk_bf16(b2[nt * 16 + q * 4 + 2], b2[nt * 16 + q * 4 + 3]);
        }
        // fp32 C-tile write offsets: feature f=nt*16+q*4+j at byte f*4,
        // 16B slot idx = nt*4+q (0..31), low-3-bit XOR swizzle, row lm*512.
        int wrOffC[8];
        #pragma unroll
        for (int nt = 0; nt < 8; ++nt)
            wrOffC[nt] = lm * 512 + (((nt * 4 + q) ^ swz) << 4);

        #pragma unroll 1
        for (int tt = 0; tt < TPB; ++tt) {
            // ---- layer 1: build Y1 fragment for this tile ----
            const int s    = tt * 16 + lm;             // 0..815
            const unsigned row = (unsigned)s / KQ;     // 0..15
            const int k    = s - (int)row * KQ;
            const float x0 = xL[row];
            const float X  = fmaf((xmax - x0) * 0.5f, sSteps[k] + 1.0f, x0);
            short8 Y1[4];
            #pragma unroll
            for (int kk = 0; kk < 4; ++kk) {
                const float* hp = hpL + row * HD + kk * 32 + q * 8;
                f32x4 ha = *(const f32x4*)hp;
                f32x4 hb = *(const f32x4*)(hp + 4);
                S8U u;
                u.u[0] = pk_bf16(fmaxf(fmaf(X, w1x[kk*8+0], ha[0]), 0.f),
                                 fmaxf(fmaf(X, w1x[kk*8+1], ha[1]), 0.f));
                u.u[1] = pk_bf16(fmaxf(fmaf(X, w1x[kk*8+2], ha[2]), 0.f),
                                 fmaxf(fmaf(X, w1x[kk*8+3], ha[3]), 0.f));
                u.u[2] = pk_bf16(fmaxf(fmaf(X, w1x[kk*8+4], hb[0]), 0.f),
                                 fmaxf(fmaf(X, w1x[kk*8+5], hb[1]), 0.f));
                u.u[3] = pk_bf16(fmaxf(fmaf(X, w1x[kk*8+6], hb[2]), 0.f),
                                 fmaxf(fmaf(X, w1x[kk*8+7], hb[3]), 0.f));
                Y1[kk] = u.s8;
            }

            // ---- layer 2: 32 MFMA, C init from packed b2 ----
            f32x4 C[8];
            #pragma unroll
            for (int nt = 0; nt < 8; ++nt) {
                unsigned u0 = b2p[2 * nt], u1 = b2p[2 * nt + 1];
                C[nt][0] = bf_lo(u0); C[nt][1] = bf_hi(u0);
                C[nt][2] = bf_lo(u1); C[nt][3] = bf_hi(u1);
            }
            #pragma unroll
            for (int kk = 0; kk < 4; ++kk)
                #pragma unroll
                for (int nt = 0; nt < 8; ++nt)
                    C[nt] = __builtin_amdgcn_mfma_f32_16x16x32_bf16(W2A[nt][kk], Y1[kk], C[nt], 0, 0, 0);

            // ---- raw fp32 handoff: no relu, no pack ----
            char* d2 = c2x[tt & 1];
            #pragma unroll
            for (int nt = 0; nt < 8; ++nt)
                *(f32x4*)(d2 + wrOffC[nt]) = C[nt];
            __syncthreads();                           // tile tt ready
        }
    } else {
        // ========== CONSUMER: relu+pack + layer 3 + layer 4 ==========
        short8  W3A[8][4];
        unsigned b3p[16];
        f32x4   W4c[8];
        #pragma unroll
        for (int nt = 0; nt < 8; ++nt) {
            #pragma unroll
            for (int kk = 0; kk < 4; ++kk) {
                const float* p3 = W3 + (nt * 16 + lm) * HD + kk * 32 + q * 8;
                S8U a3;
                #pragma unroll
                for (int j = 0; j < 4; ++j)
                    a3.u[j] = pk_bf16(p3[2 * j], p3[2 * j + 1]);
                W3A[nt][kk] = a3.s8;
            }
            b3p[2 * nt + 0] = pk_bf16(b3[nt * 16 + q * 4 + 0], b3[nt * 16 + q * 4 + 1]);
            b3p[2 * nt + 1] = pk_bf16(b3[nt * 16 + q * 4 + 2], b3[nt * 16 + q * 4 + 3]);
            W4c[nt] = *(const f32x4*)(W4 + nt * 16 + q * 4);
        }
        const float b4v = b4[0];
        // fp32 C-tile read offsets: fragment kk needs features
        // kk*32+q*8..+7 = 16B slots kk*8+q*2 and +1 (same XOR swizzle).
        int rdC0[4], rdC1[4];
        #pragma unroll
        for (int kk = 0; kk < 4; ++kk) {
            rdC0[kk] = lm * 512 + (((kk * 8 + q * 2 + 0) ^ swz) << 4);
            rdC1[kk] = lm * 512 + (((kk * 8 + q * 2 + 1) ^ swz) << 4);
        }

        #pragma unroll 1
        for (int tt = 0; tt < TPB; ++tt) {
            __syncthreads();                           // wait for tile tt
            const char* s2 = c2x[tt & 1];

            // ---- relu + pack into MFMA operands (moved from producer) ----
            short8 Y2[4];
            #pragma unroll
            for (int kk = 0; kk < 4; ++kk) {
                f32x4 r0 = *(const f32x4*)(s2 + rdC0[kk]);
                f32x4 r1 = *(const f32x4*)(s2 + rdC1[kk]);
                S8U u;
                u.u[0] = pk_bf16(fmaxf(r0[0], 0.f), fmaxf(r0[1], 0.f));
                u.u[1] = pk_bf16(fmaxf(r0[2], 0.f), fmaxf(r0[3], 0.f));
                u.u[2] = pk_bf16(fmaxf(r1[0], 0.f), fmaxf(r1[1], 0.f));
                u.u[3] = pk_bf16(fmaxf(r1[2], 0.f), fmaxf(r1[3], 0.f));
                Y2[kk] = u.s8;
            }

            // ---- layer 3: 32 MFMA, C init from packed b3 ----
            f32x4 C[8];
            #pragma unroll
            for (int nt = 0; nt < 8; ++nt) {
                unsigned u0 = b3p[2 * nt], u1 = b3p[2 * nt + 1];
                C[nt][0] = bf_lo(u0); C[nt][1] = bf_hi(u0);
                C[nt][2] = bf_lo(u1); C[nt][3] = bf_hi(u1);
            }
            #pragma unroll
            for (int kk = 0; kk < 4; ++kk)
                #pragma unroll
                for (int nt = 0; nt < 8; ++nt)
                    C[nt] = __builtin_amdgcn_mfma_f32_16x16x32_bf16(W3A[nt][kk], Y2[kk], C[nt], 0, 0, 0);

            // ---- layer 4 partial: q-reduce, defer the rest ----
            float p = 0.f;
            #pragma unroll
            for (int nt = 0; nt < 8; ++nt) {
                p = fmaf(fmaxf(C[nt][0], 0.f), W4c[nt][0], p);
                p = fmaf(fmaxf(C[nt][1], 0.f), W4c[nt][1], p);
                p = fmaf(fmaxf(C[nt][2], 0.f), W4c[nt][2], p);
                p = fmaf(fmaxf(C[nt][3], 0.f), W4c[nt][3], p);
            }
            p += __shfl_xor(p, 16);
            p += __shfl_xor(p, 32);
            if (lane < 16) vs[tt * 16 + lm] = p;
        }

        // ---- deferred epilogue: elu + ccw + row-reduce, 16 rows ----
        {
            const int r   = lane >> 2;                 // row 0..15
            const int sub = lane & 3;
            float a = 0.f;
            #pragma unroll 1
            for (int j = 0; j < 13; ++j) {
                int k = sub + 4 * j;
                if (k < KQ) {
                    float y4 = vs[r * KQ + k] + b4v;
                    float f  = (y4 > 0.f) ? (y4 + 1.f) : __expf(y4);
                    a = fmaf(f, sCcw[k], a);
                }
            }
            a += __shfl_xor(a, 1);
            a += __shfl_xor(a, 2);
            if (sub == 0)
                out[rowBase + r] = a * (xmax - xL[r]) * 0.5f;
        }
    }
}

// ---------------------------------------------------------------------------
extern "C" void kernel_launch(void* const* d_in, const int* in_sizes, int n_in,
                              void* d_out, int out_size, void* d_ws, size_t ws_size,
                              hipStream_t stream)
{
    const float* x  = (const float*)d_in[0];
    const float* h  = (const float*)d_in[1];
    const float* W1 = (const float*)d_in[2];
    const float* b1 = (const float*)d_in[3];
    const float* W2 = (const float*)d_in[4];
    const float* b2 = (const float*)d_in[5];
    const float* W3 = (const float*)d_in[6];
    const float* b3 = (const float*)d_in[7];
    const float* W4 = (const float*)d_in[8];
    const float* b4 = (const float*)d_in[9];
    float* out = (float*)d_out;

    umnn_fused<<<GRID, BLK, 0, stream>>>(x, h, W1, b1, W2, b2, W3, b3,
                                         W4, b4, out);
}

// Round 6
// 170.533 us; speedup vs baseline: 1.1765x; 1.0423x over previous
//
#include <hip/hip_runtime.h>
#include <hip/hip_bf16.h>
#include <math.h>

// ---------------------------------------------------------------------------
// Round 13: r8 structure (best: 116us) + CONSUMER-chain surgery.
// Evidence synthesis r8/r11/r12: phase critical path = CONSUMER serial chain
// (r8 with shortest consumer chain beat both rebalances despite heaviest
// producer + a 5.4MB producer spill; r12's +pack-on-consumer cost exactly
// the observed +240cyc/phase). Changes vs r8, all consumer-chain targeted:
//   1. no per-tile shuffles: consumer writes per-lane L4 partial to
//      vs4[tt*64+lane] (conflict-free); 4-way quarter sum deferred to
//      epilogue. Removes ~250 serial cyc (2 dependent ds_permute) per phase.
//   2. C-init from LDS fp32 bias tables b2f/b3f (staged once): removes the
//      32 unpack VALU ops from the chain head (reads pipeline with Y2
//      reads); ALSO -16 regs/role -> producer ~236 regs, r8 spill gone.
//   3. static asymmetric s_setprio: consumer=1, producer=0 (consumer wins
//      SIMD arbitration; r11's SYMMETRIC prio was the failure mode).
// Numerics: bias now fp32 (more accurate than r8's bf16-rounded bias);
// rest identical. absmax ~0.125 vs thr 0.4725.
// ---------------------------------------------------------------------------

#define B_N    16384
#define KQ     51
#define HD     128
#define IND    64
#define BLK    128               // 2 waves: producer + consumer
#define RPB    16                // b-rows per block
#define GRID   (B_N / RPB)       // 1024
#define TPB    ((RPB * KQ) / 16) // 51 tiles per block (exact)

typedef __attribute__((ext_vector_type(8))) short short8;
typedef __attribute__((ext_vector_type(4))) float f32x4;

union S8U { short8 s8; unsigned u[4]; };

__device__ __forceinline__ unsigned short f2bf(float f) {
    __hip_bfloat16 t = __float2bfloat16(f);
    return *reinterpret_cast<unsigned short*>(&t);
}

#if defined(__gfx950__) && defined(__has_builtin)
#if __has_builtin(__builtin_amdgcn_cvt_pk_bf16_f32)
#define HAVE_PK_BF16 1
#endif
#endif

__device__ __forceinline__ unsigned pk_bf16(float lo, float hi) {
#ifdef HAVE_PK_BF16
    typedef __attribute__((ext_vector_type(2))) __bf16 bfv2;
    bfv2 r = __builtin_amdgcn_cvt_pk_bf16_f32(lo, hi);
    return *reinterpret_cast<unsigned*>(&r);
#else
    return (unsigned)f2bf(lo) | ((unsigned)f2bf(hi) << 16);
#endif
}

__launch_bounds__(BLK, 2)
__global__ void umnn_fused(const float* __restrict__ x,  const float* __restrict__ h,
                           const float* __restrict__ W1, const float* __restrict__ b1,
                           const float* __restrict__ W2, const float* __restrict__ b2,
                           const float* __restrict__ W3, const float* __restrict__ b3,
                           const float* __restrict__ W4, const float* __restrict__ b4,
                           float* __restrict__ out)
{
    __shared__ __align__(16) float hpL[RPB * HD];      // 8 KB block hpart
    __shared__ __align__(16) char  y2x[2][4096];       // 8 KB Y2 double buffer
    __shared__ __align__(16) float hshT[63 * 20];      // 5 KB h^T staging
    __shared__ __align__(16) float vs4[TPB * 64];      // 12.75 KB per-lane partials
    __shared__ __align__(16) float b2f[HD], b3f[HD];   // 1 KB fp32 bias tables
    __shared__ float xL[RPB];
    __shared__ float sSteps[KQ], sCcw[KQ];
    __shared__ float red2[2];

    const int tid  = threadIdx.x;
    const int w    = tid >> 6;
    const int lane = tid & 63;
    const int q    = lane >> 4;
    const int lm   = lane & 15;
    const int swz  = lm & 7;
    const int rowBase = blockIdx.x * RPB;

    // ---- CC tables (validated r4 formula) ----
    if (tid < KQ) {
        const int j = tid;
        const float pi50 = 0.06283185307179586f;
        sSteps[j] = __cosf((float)j * pi50);
        float s = 0.0f;
        for (int i = 0; i <= 50; i += 2) {
            float Wi = (i == 0) ? 1.0f : 2.0f / (1.0f - (float)(i * i));
            float lam;
            if (j == 0) lam = 0.5f;
            else {
                int mp = (i * j) % 100;
                lam = __cosf((float)mp * pi50);
                if (j == 50) lam *= 0.5f;
            }
            s += (lam * 0.04f) * Wi;
        }
        sCcw[j] = s;
    }
    // ---- fp32 bias tables ----
    if (tid < HD) {
        b2f[tid] = b2[tid];
        b3f[tid] = b3[tid];
    }
    // ---- xmax scan (x: 64 KB, cache-resident) ----
    {
        const f32x4* x4 = (const f32x4*)x;
        float mx = -1e30f;
        for (int i = tid; i < B_N / 4; i += BLK) {
            f32x4 v = x4[i];
            mx = fmaxf(fmaxf(mx, fmaxf(v[0], v[1])), fmaxf(v[2], v[3]));
        }
        #pragma unroll
        for (int d = 32; d > 0; d >>= 1) mx = fmaxf(mx, __shfl_xor(mx, d));
        if (lane == 0) red2[w] = mx;
    }
    // ---- stage h^T for this block's 16 rows; init xL ----
    for (int i = tid; i < RPB * 63; i += BLK) {
        int r = i / 63, d = i - r * 63;
        hshT[d * 20 + r] = h[rowBase * 63 + i];
    }
    if (tid < RPB) xL[tid] = x[rowBase + tid];
    __syncthreads();                                   // B1

    const float xmax = fmaxf(red2[0], red2[1]) + 10.0f;

    // ---- block hpart: thread tid = feature n, 16 row-accumulators ----
    {
        const int n = tid;
        float acc[RPB];
        const float b1v = b1[n];
        #pragma unroll
        for (int r = 0; r < RPB; ++r) acc[r] = b1v;
        const float* wr = W1 + n * IND + 1;
        #pragma unroll 1
        for (int d = 0; d < IND - 1; ++d) {
            float wv = wr[d];
            const float* ht = hshT + d * 20;
            #pragma unroll
            for (int rc = 0; rc < RPB / 4; ++rc) {
                f32x4 hv = *(const f32x4*)(ht + rc * 4);
                acc[rc * 4 + 0] = fmaf(wv, hv[0], acc[rc * 4 + 0]);
                acc[rc * 4 + 1] = fmaf(wv, hv[1], acc[rc * 4 + 1]);
                acc[rc * 4 + 2] = fmaf(wv, hv[2], acc[rc * 4 + 2]);
                acc[rc * 4 + 3] = fmaf(wv, hv[3], acc[rc * 4 + 3]);
            }
        }
        #pragma unroll
        for (int r = 0; r < RPB; ++r) hpL[r * HD + n] = acc[r];
    }
    __syncthreads();                                   // B2 (hpL ready)

    // per-lane C-init byte offset into bias table: feature nt*16+q*4
    const int bIoff = q * 16;                          // + nt*64 at use site

    if (w == 0) {
        // ================= PRODUCER: layer 1 + layer 2 =================
        __builtin_amdgcn_s_setprio(0);
        float w1x[32];
        #pragma unroll
        for (int kk = 0; kk < 4; ++kk)
            #pragma unroll
            for (int j = 0; j < 8; ++j)
                w1x[kk * 8 + j] = W1[(kk * 32 + q * 8 + j) * IND];

        short8 W2A[8][4];
        #pragma unroll
        for (int nt = 0; nt < 8; ++nt) {
            #pragma unroll
            for (int kk = 0; kk < 4; ++kk) {
                const float* p2 = W2 + (nt * 16 + lm) * HD + kk * 32 + q * 8;
                S8U a2;
                #pragma unroll
                for (int j = 0; j < 4; ++j)
                    a2.u[j] = pk_bf16(p2[2 * j], p2[2 * j + 1]);
                W2A[nt][kk] = a2.s8;
            }
        }
        int wrOff[8];
        #pragma unroll
        for (int nt = 0; nt < 8; ++nt)
            wrOff[nt] = lm * 256 + (((2 * nt + (q >> 1)) ^ swz) << 4) + ((q & 1) << 3);
        const char* b2c = (const char*)b2f;

        #pragma unroll 1
        for (int tt = 0; tt < TPB; ++tt) {
            // ---- layer 1: build Y1 fragment for this tile ----
            const int s    = tt * 16 + lm;             // 0..815
            const unsigned row = (unsigned)s / KQ;     // 0..15
            const int k    = s - (int)row * KQ;
            const float x0 = xL[row];
            const float X  = fmaf((xmax - x0) * 0.5f, sSteps[k] + 1.0f, x0);
            short8 Y1[4];
            #pragma unroll
            for (int kk = 0; kk < 4; ++kk) {
                const float* hp = hpL + row * HD + kk * 32 + q * 8;
                f32x4 ha = *(const f32x4*)hp;
                f32x4 hb = *(const f32x4*)(hp + 4);
                S8U u;
                u.u[0] = pk_bf16(fmaxf(fmaf(X, w1x[kk*8+0], ha[0]), 0.f),
                                 fmaxf(fmaf(X, w1x[kk*8+1], ha[1]), 0.f));
                u.u[1] = pk_bf16(fmaxf(fmaf(X, w1x[kk*8+2], ha[2]), 0.f),
                                 fmaxf(fmaf(X, w1x[kk*8+3], ha[3]), 0.f));
                u.u[2] = pk_bf16(fmaxf(fmaf(X, w1x[kk*8+4], hb[0]), 0.f),
                                 fmaxf(fmaf(X, w1x[kk*8+5], hb[1]), 0.f));
                u.u[3] = pk_bf16(fmaxf(fmaf(X, w1x[kk*8+6], hb[2]), 0.f),
                                 fmaxf(fmaf(X, w1x[kk*8+7], hb[3]), 0.f));
                Y1[kk] = u.s8;
            }

            // ---- layer 2: C init from LDS bias table, 32 MFMA ----
            f32x4 C[8];
            #pragma unroll
            for (int nt = 0; nt < 8; ++nt)
                C[nt] = *(const f32x4*)(b2c + nt * 64 + bIoff);
            #pragma unroll
            for (int kk = 0; kk < 4; ++kk)
                #pragma unroll
                for (int nt = 0; nt < 8; ++nt)
                    C[nt] = __builtin_amdgcn_mfma_f32_16x16x32_bf16(W2A[nt][kk], Y1[kk], C[nt], 0, 0, 0);

            // ---- relu + pack + write Y2 (producer rides in C's shadow) ----
            char* d2 = y2x[tt & 1];
            #pragma unroll
            for (int nt = 0; nt < 8; ++nt) {
                unsigned lo = pk_bf16(fmaxf(C[nt][0], 0.f), fmaxf(C[nt][1], 0.f));
                unsigned hi = pk_bf16(fmaxf(C[nt][2], 0.f), fmaxf(C[nt][3], 0.f));
                *(int2*)(d2 + wrOff[nt]) = make_int2((int)lo, (int)hi);
            }
            __syncthreads();                           // tile tt ready
        }
    } else {
        // ================= CONSUMER: layer 3 + layer 4 =================
        __builtin_amdgcn_s_setprio(1);                 // consumer is critical
        short8 W3A[8][4];
        f32x4  W4c[8];
        #pragma unroll
        for (int nt = 0; nt < 8; ++nt) {
            #pragma unroll
            for (int kk = 0; kk < 4; ++kk) {
                const float* p3 = W3 + (nt * 16 + lm) * HD + kk * 32 + q * 8;
                S8U a3;
                #pragma unroll
                for (int j = 0; j < 4; ++j)
                    a3.u[j] = pk_bf16(p3[2 * j], p3[2 * j + 1]);
                W3A[nt][kk] = a3.s8;
            }
            W4c[nt] = *(const f32x4*)(W4 + nt * 16 + q * 4);
        }
        const float b4v = b4[0];
        int rdOff[4];
        #pragma unroll
        for (int kk = 0; kk < 4; ++kk)
            rdOff[kk] = lm * 256 + (((kk * 4 + q) ^ swz) << 4);
        const char* b3c = (const char*)b3f;

        #pragma unroll 1
        for (int tt = 0; tt < TPB; ++tt) {
            __syncthreads();                           // wait for tile tt
            const char* s2 = y2x[tt & 1];

            // chain head: Y2 reads + C-init reads, all pipelined LDS
            short8 Y2[4];
            #pragma unroll
            for (int kk = 0; kk < 4; ++kk)
                Y2[kk] = *(const short8*)(s2 + rdOff[kk]);
            f32x4 C[8];
            #pragma unroll
            for (int nt = 0; nt < 8; ++nt)
                C[nt] = *(const f32x4*)(b3c + nt * 64 + bIoff);

            #pragma unroll
            for (int kk = 0; kk < 4; ++kk)
                #pragma unroll
                for (int nt = 0; nt < 8; ++nt)
                    C[nt] = __builtin_amdgcn_mfma_f32_16x16x32_bf16(W3A[nt][kk], Y2[kk], C[nt], 0, 0, 0);

            // ---- layer 4 per-lane partial: NO shuffles, straight to LDS ----
            float p = 0.f;
            #pragma unroll
            for (int nt = 0; nt < 8; ++nt) {
                p = fmaf(fmaxf(C[nt][0], 0.f), W4c[nt][0], p);
                p = fmaf(fmaxf(C[nt][1], 0.f), W4c[nt][1], p);
                p = fmaf(fmaxf(C[nt][2], 0.f), W4c[nt][2], p);
                p = fmaf(fmaxf(C[nt][3], 0.f), W4c[nt][3], p);
            }
            vs4[tt * 64 + lane] = p;                   // conflict-free
        }

        // ---- deferred epilogue: 4-way quarter sum + elu + ccw + reduce ----
        {
            const int r   = lane >> 2;                 // row 0..15
            const int sub = lane & 3;
            float a = 0.f;
            #pragma unroll 1
            for (int j = 0; j < 13; ++j) {
                int k = sub + 4 * j;
                if (k < KQ) {
                    int s   = r * KQ + k;
                    int tt  = s >> 4;
                    int lm2 = s & 15;
                    const float* vb = vs4 + tt * 64 + lm2;
                    float y4 = vb[0] + vb[16] + vb[32] + vb[48] + b4v;
                    float f  = (y4 > 0.f) ? (y4 + 1.f) : __expf(y4);
                    a = fmaf(f, sCcw[k], a);
                }
            }
            a += __shfl_xor(a, 1);
            a += __shfl_xor(a, 2);
            if (sub == 0)
                out[rowBase + r] = a * (xmax - xL[r]) * 0.5f;
        }
    }
}

// ---------------------------------------------------------------------------
extern "C" void kernel_launch(void* const* d_in, const int* in_sizes, int n_in,
                              void* d_out, int out_size, void* d_ws, size_t ws_size,
                              hipStream_t stream)
{
    const float* x  = (const float*)d_in[0];
    const float* h  = (const float*)d_in[1];
    const float* W1 = (const float*)d_in[2];
    const float* b1 = (const float*)d_in[3];
    const float* W2 = (const float*)d_in[4];
    const float* b2 = (const float*)d_in[5];
    const float* W3 = (const float*)d_in[6];
    const float* b3 = (const float*)d_in[7];
    const float* W4 = (const float*)d_in[8];
    const float* b4 = (const float*)d_in[9];
    float* out = (float*)d_out;

    umnn_fused<<<GRID, BLK, 0, stream>>>(x, h, W1, b1, W2, b2, W3, b3,
                                         W4, b4, out);
}